// Round 11
// baseline (195.406 us; speedup 1.0000x reference)
//
#include <hip/hip_runtime.h>
#include <hip/hip_bf16.h>
#include <string.h>

// MultiHeadAttention: B=1, L=4096, D=1024, H=16, HD=64, causal.
// R23:
//  - attn_fwd: byte-identical to R21 (62 us, deterministic). R20/R22's
//    deeper-pipeline attempts both corrupted un-localizably -> axis closed.
//  - gemm_qkv/gemm_proj: rebuilt as TRUE 2-phase double-buffer (m97/T3-min
//    pattern). Old structure stalled every K-step on the loads it had just
//    issued (barrier; stage; barrier[vmcnt-drain]; compute). New: stage(t+1)
//    issues BEFORE compute(t); one barrier per BK=32 step; the next barrier
//    drains t+1 after 16 MFMAs of overlap. Accumulation order unchanged
//    (ascending kb, same MFMA sequence) -> bit-identical results.
//  - LDS: qkv 32KB (keeps 3 blocks/CU, grid is exactly 768 = 3/CU),
//    proj 24KB (2 blocks/CU).

typedef unsigned short ushort_t;
typedef __attribute__((ext_vector_type(8))) short short8;
typedef __attribute__((ext_vector_type(4))) float f32x4;

#define MFMA16(a, b, c) __builtin_amdgcn_mfma_f32_16x16x32_bf16(a, b, c, 0, 0, 0)

static constexpr int Lq = 4096;
static constexpr int Dm = 1024;
static constexpr int NH = 16;
static constexpr int HD = 64;
static constexpr int D3 = 3072;
static constexpr float SCALE_LOG2E = 0.125f * 1.44269504088896340736f;

__device__ __forceinline__ ushort_t f2bf(float f) {
    union { float f; unsigned int u; } x{f};
    unsigned int u = x.u;
    u += 0x7fffu + ((u >> 16) & 1u);   // RNE
    return (ushort_t)(u >> 16);
}

// packed fp32x2 -> bf16x2, hardware RNE (lo = a, hi = b)
__device__ __forceinline__ unsigned int cvtpk(float a, float b) {
    unsigned int r;
    asm("v_cvt_pk_bf16_f32 %0, %1, %2" : "=v"(r) : "v"(a), "v"(b));
    return r;
}

__device__ __forceinline__ void gl2lds16(const ushort_t* g, ushort_t* l) {
    __builtin_amdgcn_global_load_lds(
        (const __attribute__((address_space(1))) unsigned int*)g,
        (__attribute__((address_space(3))) unsigned int*)l, 16, 0, 0);
}

// ---------------- prep: cvt X->bf16 + transpose-convert both W ----------------
__global__ void __launch_bounds__(256)
prep(const float* __restrict__ X, const float* __restrict__ Wqkv,
     const float* __restrict__ Wproj, ushort_t* __restrict__ Xb,
     ushort_t* __restrict__ WqkvT, ushort_t* __restrict__ WprojT) {
    __shared__ float tile[32][33];
    const int bid = blockIdx.x, tid = threadIdx.x;
    if (bid < 4096) {
        int i = (bid * 256 + tid) * 4;
        float4 v = *(const float4*)&X[i];
        ushort_t r[4] = { f2bf(v.x), f2bf(v.y), f2bf(v.z), f2bf(v.w) };
        *(uint2*)&Xb[i] = *(uint2*)r;
        return;
    }
    const float* W; ushort_t* Wt; int Nd, nb, kb;
    if (bid < 7168) {
        int b = bid - 4096; W = Wqkv;  Wt = WqkvT;  Nd = 3072;
        nb = (b % 96) * 32; kb = (b / 96) * 32;
    } else {
        int b = bid - 7168; W = Wproj; Wt = WprojT; Nd = 1024;
        nb = (b % 32) * 32; kb = (b / 32) * 32;
    }
    const int tx = tid & 31, ty = tid >> 5;
    for (int j = 0; j < 32; j += 8)
        tile[ty + j][tx] = W[(size_t)(kb + ty + j) * Nd + nb + tx];
    __syncthreads();
    for (int j = 0; j < 32; j += 8)
        Wt[(size_t)(nb + ty + j) * Dm + kb + tx] = f2bf(tile[tx][ty + j]);
}

// ---------------- QKV GEMM (BK=32, 2-phase double-buffer, XCD-swizzled) -----
// cols [0,1024): *SCALE_LOG2E -> qkvB (Q); [1024,2048): -> qkvB (K);
// [2048,3072): transposed+key-permuted (pos = rotl2(token) per 64-window) to
// Vt via packed b128 stores.
__global__ void __launch_bounds__(256, 3)
gemm_qkv(const ushort_t* __restrict__ A, const ushort_t* __restrict__ Bt,
         const float* __restrict__ bias, ushort_t* __restrict__ Cq,
         ushort_t* __restrict__ Vt) {
    __shared__ alignas(16) ushort_t Alds[2][128 * 32];   // [buf][row*32+cc*8]
    __shared__ alignas(16) ushort_t Blds[2][128 * 32];
    const int tid  = threadIdx.x;
    const int lane = tid & 63;
    const int w    = tid >> 6;
    const int quad = lane >> 4;
    const int l16  = lane & 15;
    // chunked XCD swizzle: 768 blocks, 96 consecutive per XCD.
    const int lin0 = blockIdx.y * 32 + blockIdx.x;
    const int lin  = (lin0 & 7) * 96 + (lin0 >> 3);
    const int mbase = (lin & 31) * 128;
    const int nbase = (lin >> 5) * 128;
    const int moff  = (w >> 1) * 64;
    const int noff  = (w & 1) * 64;
    const int K = Dm;

    f32x4 acc[4][4] = {};

    // stage BK=32 tile at column kb into buffer b (2 gl2lds per array/thread)
    auto stage = [&](int b, int kb) {
        #pragma unroll
        for (int c = 0; c < 2; c++) {
            const int id  = w * 128 + c * 64 + lane;
            const int row = id >> 2, col = (id & 3) * 8;
            gl2lds16(&A[(size_t)(mbase + row) * K + kb + col],
                     &Alds[b][(size_t)(w * 128 + c * 64) * 8]);
            gl2lds16(&Bt[(size_t)(nbase + row) * K + kb + col],
                     &Blds[b][(size_t)(w * 128 + c * 64) * 8]);
        }
    };

    stage(0, 0);
    int cur = 0;
    for (int t = 0; t < 32; t++) {
        __syncthreads();                       // tile t staged & buf cur^1 free
        if (t + 1 < 32) stage(cur ^ 1, (t + 1) * 32);
        short8 a[4], b[4];
        #pragma unroll
        for (int m = 0; m < 4; m++)
            a[m] = *(const short8*)&Alds[cur][(moff + m * 16 + l16) * 32 + quad * 8];
        #pragma unroll
        for (int n = 0; n < 4; n++)
            b[n] = *(const short8*)&Blds[cur][(noff + n * 16 + l16) * 32 + quad * 8];
        #pragma unroll
        for (int m = 0; m < 4; m++)
            #pragma unroll
            for (int n = 0; n < 4; n++)
                acc[m][n] = MFMA16(a[m], b[n], acc[m][n]);
        cur ^= 1;
    }

    if (nbase < 2048) {
        const bool qscale = (nbase < 1024);
        #pragma unroll
        for (int m = 0; m < 4; m++)
            #pragma unroll
            for (int n = 0; n < 4; n++)
                #pragma unroll
                for (int r = 0; r < 4; r++) {
                    int row = mbase + moff + m * 16 + quad * 4 + r;
                    int col = nbase + noff + n * 16 + l16;
                    float v = acc[m][n][r] + bias[col];
                    if (qscale) v *= SCALE_LOG2E;
                    Cq[(size_t)row * D3 + col] = f2bf(v);
                }
    } else {
        // V block: token64 = m*16 + quad*4 + r -> pos = (quad*4+r)*4 + m.
        const int dbase = nbase - 2048 + noff;
        const size_t kb0 = (size_t)mbase + moff;   // 64-aligned key window
        #pragma unroll
        for (int n = 0; n < 4; n++) {
            const float bv = bias[nbase + noff + n * 16 + l16];
            ushort_t* vrow = Vt + (size_t)(dbase + n * 16 + l16) * Lq + kb0 + quad * 16;
            #pragma unroll
            for (int rp = 0; rp < 2; rp++) {
                ushort_t pk[8];
                #pragma unroll
                for (int dr = 0; dr < 2; dr++)
                    #pragma unroll
                    for (int m = 0; m < 4; m++)
                        pk[dr * 4 + m] = f2bf(acc[m][n][2 * rp + dr] + bv);
                *(short8*)(vrow + rp * 8) = *(const short8*)pk;
            }
        }
    }
}

// ---------------- flash attention (R21, unchanged) ----------------
// grid 256 = 16 pairs x 16 heads; head = bid & 15 (XCD pin); p = bid >> 4.
// block 1024 = 16 waves: sub = w&3 (32 q-rows), qtr = w>>2 (32 key-positions).
// sel 0: chunk p; sel 1: chunk 31-p => 33 rounds/block, uniform.
// Key permutation: QK chunk s out-row quad*4+r4 == PV-key quad*8+s*4+r4, so
// pP[m] is directly the K=32 PV B-fragment. True token of PV-key:
// tok = r4*16 + (qtr&1)*8 + quad*2 + s (for masking).
__global__ void __launch_bounds__(1024)
attn_fwd(const ushort_t* __restrict__ qkv, const ushort_t* __restrict__ Vt,
         ushort_t* __restrict__ O) {
    union SMem {
        struct { ushort_t K[2][2][64 * 64]; ushort_t V[2][2][64 * 64]; } kv;
        float Ml[3 * 256 * 35];             // 34 floats/thread, pitch 35
    };
    __shared__ SMem sm;

    const int tid  = threadIdx.x;
    const int lane = tid & 63;
    const int w    = tid >> 6;          // [0,16)
    const int qtr  = w >> 2;            // key quarter [0,4)
    const int sub  = w & 3;             // q sub-chunk (32 rows)
    const int quad = lane >> 4;
    const int l16  = lane & 15;
    const int bid  = blockIdx.x;
    const int h    = bid & 15;
    const int p    = bid >> 4;          // [0,16)
    const float NEG_INF = -__builtin_inff();

    const ushort_t* kbase = qkv + Dm + h * HD;           // K rows, stride D3
    const ushort_t* vbase = Vt + (size_t)h * HD * Lq;    // V^T rows, stride Lq

    // K fragment: A-row i (=l16) of chunk s holds token
    //   tok = (i&3)*16 + (qtr&1)*8 + ((i>>2)&3)*2 + s
    // Read slot fk matches staging swizzle g'(tok) = ((tok>>4)&3)*2+((tok>>1)&1).
    int koff[2][2];
    #pragma unroll
    for (int s = 0; s < 2; s++) {
        const int tok = (l16 & 3) * 16 + (qtr & 1) * 8 + ((l16 >> 2) & 3) * 2 + s;
        const int fk  = ((l16 & 3) << 1) | ((l16 >> 2) & 1);
        #pragma unroll
        for (int kh = 0; kh < 2; kh++)
            koff[s][kh] = tok * 64 + (((kh * 4 + quad) ^ fk) * 8);
    }
    // V fragment (K=32 A-frag): row = t4*16+l16 (d), keys = contiguous 8
    // positions (qtr&1)*32 + quad*8..+7 -> one b128 per t4.
    int voff[4];
    #pragma unroll
    for (int t4 = 0; t4 < 4; t4++) {
        const int row = t4 * 16 + l16;
        voff[t4] = row * 64 + (((((qtr & 1) * 4) + quad) ^ (row & 7)) * 8);
    }
    // true-token base for masking: r*128 + kmc2 + s + r4*16
    const int kmc2 = (qtr >> 1) * 64 + (qtr & 1) * 8 + quad * 2;

    // staging: waves 0-7 stage K (both 64-tiles), waves 8-15 stage V.
    const int  tv  = tid & 511;
    const int  rr  = tv >> 3;
    const int  ccK = (tv & 7) ^ ((((rr >> 4) & 3) << 1) | ((rr >> 1) & 1));
    const int  ccV = (tv & 7) ^ (rr & 7);
    const bool isK = (tid < 512);
    const int  dsto = (w & 7) * 512;
    const ushort_t* kse = kbase + (size_t)rr * D3 + ccK * 8;
    const ushort_t* vse = vbase + (size_t)rr * Lq + ccV * 8;

    for (int sel = 0; sel < 2; sel++) {
        const int c      = sel ? (31 - p) : p;
        const int qc     = c * 128;
        const int rounds = c + 1;
        const int qrow0  = qc + sub * 32;

        short8 qf[2][2];
        #pragma unroll
        for (int m = 0; m < 2; m++) {
            const ushort_t* qr = qkv + (size_t)(qrow0 + m * 16 + l16) * D3 + h * HD;
            qf[m][0] = *(const short8*)(qr + quad * 8);
            qf[m][1] = *(const short8*)(qr + 32 + quad * 8);
        }

        f32x4 o[2][4] = {};
        float sacc[2] = { 0.f, 0.f };

        const ushort_t* kp = kse;
        const ushort_t* vp = vse;

        auto stage = [&](int b) {
            if (isK) {
                gl2lds16(kp,           &sm.kv.K[0][b][dsto]);
                gl2lds16(kp + 64 * D3, &sm.kv.K[1][b][dsto]);
            } else {
                gl2lds16(vp,           &sm.kv.V[0][b][dsto]);
                gl2lds16(vp + 64,      &sm.kv.V[1][b][dsto]);
            }
            kp += (size_t)128 * D3;
            vp += 128;
        };

        stage(0);

        for (int r = 0; r < rounds; r++) {
            const int buf = r & 1;
            __syncthreads();
            if (r + 1 < rounds) stage(buf ^ 1);

            const ushort_t* Kb = &sm.kv.K[qtr >> 1][buf][0];
            const ushort_t* Vb = &sm.kv.V[qtr >> 1][buf][0];
            const bool domask = (r == rounds - 1);
            const int qg0 = qrow0 + l16;

            // K fragments, then QK for m=0
            short8 kf[2][2];
            #pragma unroll
            for (int s = 0; s < 2; s++)
                #pragma unroll
                for (int kh = 0; kh < 2; kh++)
                    kf[s][kh] = *(const short8*)&Kb[koff[s][kh]];

            f32x4 st0[2], st1[2];
            #pragma unroll
            for (int s = 0; s < 2; s++) {
                f32x4 t = {};
                t = MFMA16(kf[s][0], qf[0][0], t);
                t = MFMA16(kf[s][1], qf[0][1], t);
                st0[s] = t;
            }

            // V fragments issue under QK[m0]'s shadow; then QK for m=1
            short8 vf[4];
            #pragma unroll
            for (int t4 = 0; t4 < 4; t4++)
                vf[t4] = *(const short8*)&Vb[voff[t4]];

            #pragma unroll
            for (int s = 0; s < 2; s++) {
                f32x4 t = {};
                t = MFMA16(kf[s][0], qf[1][0], t);
                t = MFMA16(kf[s][1], qf[1][1], t);
                st1[s] = t;
            }

            // exp2 + pack m0 (VALU; overlaps QK[m1] MFMA)
            short8 pP0;
            {
                union { unsigned int u4[4]; short8 s8; } pb;
                #pragma unroll
                for (int s = 0; s < 2; s++) {
                    float e[4];
                    #pragma unroll
                    for (int r4 = 0; r4 < 4; r4++) {
                        float v = st0[s][r4];
                        if (domask && (r * 128 + kmc2 + s + r4 * 16 > qg0))
                            v = NEG_INF;
                        e[r4] = __builtin_amdgcn_exp2f(v);
                    }
                    sacc[0] += (e[0] + e[1]) + (e[2] + e[3]);
                    pb.u4[s * 2]     = cvtpk(e[0], e[1]);
                    pb.u4[s * 2 + 1] = cvtpk(e[2], e[3]);
                }
                pP0 = pb.s8;
            }

            // PV m0 (MFMA; overlaps exp2 m1 below)
            #pragma unroll
            for (int t4 = 0; t4 < 4; t4++)
                o[0][t4] = MFMA16(vf[t4], pP0, o[0][t4]);

            // exp2 + pack m1
            short8 pP1;
            {
                union { unsigned int u4[4]; short8 s8; } pb;
                #pragma unroll
                for (int s = 0; s < 2; s++) {
                    float e[4];
                    #pragma unroll
                    for (int r4 = 0; r4 < 4; r4++) {
                        float v = st1[s][r4];
                        if (domask && (r * 128 + kmc2 + s + r4 * 16 > qg0 + 16))
                            v = NEG_INF;
                        e[r4] = __builtin_amdgcn_exp2f(v);
                    }
                    sacc[1] += (e[0] + e[1]) + (e[2] + e[3]);
                    pb.u4[s * 2]     = cvtpk(e[0], e[1]);
                    pb.u4[s * 2 + 1] = cvtpk(e[2], e[3]);
                }
                pP1 = pb.s8;
            }

            // PV m1
            #pragma unroll
            for (int t4 = 0; t4 < 4; t4++)
                o[1][t4] = MFMA16(vf[t4], pP1, o[1][t4]);
        }

        // reduce sacc across quads (keys of this quarter fully summed)
        #pragma unroll
        for (int m = 0; m < 2; m++) {
            sacc[m] += __shfl_xor(sacc[m], 16);
            sacc[m] += __shfl_xor(sacc[m], 32);
        }

        // 4-way merge through Ml (aliases K/V LDS; rounds done, barriers
        // separate all uses).
        __syncthreads();
        if (qtr != 0) {
            float* dst = sm.Ml + (size_t)((qtr - 1) * 256 + sub * 64 + lane) * 35;
            #pragma unroll
            for (int m = 0; m < 2; m++)
                #pragma unroll
                for (int t4 = 0; t4 < 4; t4++)
                    *(f32x4*)(dst + (m * 4 + t4) * 4) = o[m][t4];
            dst[32] = sacc[0];
            dst[33] = sacc[1];
        }
        __syncthreads();
        if (qtr == 0) {
            #pragma unroll
            for (int j = 0; j < 3; j++) {
                const float* src = sm.Ml + (size_t)(j * 256 + sub * 64 + lane) * 35;
                #pragma unroll
                for (int m = 0; m < 2; m++)
                    #pragma unroll
                    for (int t4 = 0; t4 < 4; t4++)
                        o[m][t4] += *(const f32x4*)(src + (m * 4 + t4) * 4);
                sacc[0] += src[32];
                sacc[1] += src[33];
            }
            #pragma unroll
            for (int m = 0; m < 2; m++) {
                const float inv = 1.0f / sacc[m];
                ushort_t* orow = O + (size_t)(qrow0 + m * 16 + l16) * Dm + h * HD;
                #pragma unroll
                for (int t4 = 0; t4 < 4; t4++) {
                    ushort_t pk[4];
                    #pragma unroll
                    for (int r4 = 0; r4 < 4; r4++)
                        pk[r4] = f2bf(o[m][t4][r4] * inv);
                    *(uint2*)(orow + t4 * 16 + quad * 4) = *(const uint2*)pk;
                }
            }
        }
        __syncthreads();
    }
}

// ---------------- proj GEMM: 128x64, BK=32 double-buffer, XCD-swizzled ------
__global__ void __launch_bounds__(256, 2)
gemm_proj(const ushort_t* __restrict__ A, const ushort_t* __restrict__ Bt,
          const float* __restrict__ bias, float* __restrict__ C) {
    __shared__ alignas(16) ushort_t Alds[2][128 * 32];
    __shared__ alignas(16) ushort_t Blds[2][64 * 32];
    const int tid  = threadIdx.x;
    const int lane = tid & 63;
    const int w    = tid >> 6;
    const int quad = lane >> 4;
    const int l16  = lane & 15;
    // chunked XCD swizzle: 512 blocks, 64 consecutive per XCD.
    const int lin0 = blockIdx.y * 32 + blockIdx.x;
    const int lin  = (lin0 & 7) * 64 + (lin0 >> 3);
    const int mbase = (lin & 31) * 128;
    const int nbase = (lin >> 5) * 64;
    const int moff  = (w >> 1) * 64;
    const int noff  = (w & 1) * 32;
    const int K = Dm, N = Dm;

    f32x4 acc[4][2] = {};

    auto stage = [&](int bf, int kb) {
        #pragma unroll
        for (int c = 0; c < 2; c++) {
            const int id  = w * 128 + c * 64 + lane;
            const int row = id >> 2, col = (id & 3) * 8;
            gl2lds16(&A[(size_t)(mbase + row) * K + kb + col],
                     &Alds[bf][(size_t)(w * 128 + c * 64) * 8]);
        }
        {
            const int id  = w * 64 + lane;
            const int row = id >> 2, col = (id & 3) * 8;
            gl2lds16(&Bt[(size_t)(nbase + row) * K + kb + col],
                     &Blds[bf][(size_t)(w * 64) * 8]);
        }
    };

    stage(0, 0);
    int cur = 0;
    for (int t = 0; t < 32; t++) {
        __syncthreads();
        if (t + 1 < 32) stage(cur ^ 1, (t + 1) * 32);
        short8 a[4], b[2];
        #pragma unroll
        for (int m = 0; m < 4; m++)
            a[m] = *(const short8*)&Alds[cur][(moff + m * 16 + l16) * 32 + quad * 8];
        #pragma unroll
        for (int n = 0; n < 2; n++)
            b[n] = *(const short8*)&Blds[cur][(noff + n * 16 + l16) * 32 + quad * 8];
        #pragma unroll
        for (int m = 0; m < 4; m++)
            #pragma unroll
            for (int n = 0; n < 2; n++)
                acc[m][n] = MFMA16(a[m], b[n], acc[m][n]);
        cur ^= 1;
    }

    #pragma unroll
    for (int m = 0; m < 4; m++)
        #pragma unroll
        for (int n = 0; n < 2; n++)
            #pragma unroll
            for (int r = 0; r < 4; r++) {
                int row = mbase + moff + m * 16 + quad * 4 + r;
                int col = nbase + noff + n * 16 + l16;
                C[(size_t)row * N + col] = acc[m][n][r] + bias[col];
            }
}

// ---------------- launch ----------------
extern "C" void kernel_launch(void* const* d_in, const int* in_sizes, int n_in,
                              void* d_out, int out_size, void* d_ws, size_t ws_size,
                              hipStream_t stream) {
    const float* X     = (const float*)d_in[0];
    const float* Wqkv  = (const float*)d_in[1];
    const float* bqkv  = (const float*)d_in[2];
    const float* Wproj = (const float*)d_in[3];
    const float* bproj = (const float*)d_in[4];
    float* out = (float*)d_out;

    ushort_t* ws     = (ushort_t*)d_ws;
    ushort_t* Xb     = ws;                               // 4096x1024
    ushort_t* WqkvT  = Xb + (size_t)Lq * Dm;             // 3072x1024
    ushort_t* WprojT = WqkvT + (size_t)D3 * Dm;          // 1024x1024
    ushort_t* qkvB   = WprojT + (size_t)Dm * Dm;         // 4096x3072 (Q,K used)
    ushort_t* VtB    = qkvB + (size_t)Lq * D3;           // 16x64x4096
    ushort_t* Ob     = VtB + (size_t)NH * HD * Lq;       // 4096x1024

    prep<<<dim3(8192), 256, 0, stream>>>(X, Wqkv, Wproj, Xb, WqkvT, WprojT);

    gemm_qkv<<<dim3(Lq / 128, D3 / 128), 256, 0, stream>>>(
        Xb, WqkvT, bqkv, qkvB, VtB);

    attn_fwd<<<dim3(256), 1024, 0, stream>>>(qkvB, VtB, Ob);

    gemm_proj<<<dim3(Lq / 128, Dm / 64), 256, 0, stream>>>(
        Ob, WprojT, bproj, out);
}

// Round 13
// 192.902 us; speedup vs baseline: 1.0130x; 1.0130x over previous
//
#include <hip/hip_runtime.h>
#include <hip/hip_bf16.h>
#include <string.h>

// MultiHeadAttention: B=1, L=4096, D=1024, H=16, HD=64, causal.
// R25 = R24 resubmitted (previous round was an infra failure, never measured):
//  - attn_fwd + gemm_qkv: R21 byte-exact (best measured: attn 62+-2.5us,
//    non-attn 126-129us). R23's BK=32 gemm dbuf regressed ~5us -> reverted.
//  - gemm_proj: tile 128x64 -> 128x128 reusing gemm_qkv's proven BK=64
//    kk-split loop (32KB LDS, 256 blocks = 1/CU): 2x B-panel reuse and 2x
//    MFMA per barrier on a 16-K-step kernel that is barrier-dominated.
//    Isolated change - revertible without touching attn/qkv.

typedef unsigned short ushort_t;
typedef __attribute__((ext_vector_type(8))) short short8;
typedef __attribute__((ext_vector_type(4))) float f32x4;

#define MFMA16(a, b, c) __builtin_amdgcn_mfma_f32_16x16x32_bf16(a, b, c, 0, 0, 0)

static constexpr int Lq = 4096;
static constexpr int Dm = 1024;
static constexpr int NH = 16;
static constexpr int HD = 64;
static constexpr int D3 = 3072;
static constexpr float SCALE_LOG2E = 0.125f * 1.44269504088896340736f;

__device__ __forceinline__ ushort_t f2bf(float f) {
    union { float f; unsigned int u; } x{f};
    unsigned int u = x.u;
    u += 0x7fffu + ((u >> 16) & 1u);   // RNE
    return (ushort_t)(u >> 16);
}

// packed fp32x2 -> bf16x2, hardware RNE (lo = a, hi = b)
__device__ __forceinline__ unsigned int cvtpk(float a, float b) {
    unsigned int r;
    asm("v_cvt_pk_bf16_f32 %0, %1, %2" : "=v"(r) : "v"(a), "v"(b));
    return r;
}

__device__ __forceinline__ void gl2lds16(const ushort_t* g, ushort_t* l) {
    __builtin_amdgcn_global_load_lds(
        (const __attribute__((address_space(1))) unsigned int*)g,
        (__attribute__((address_space(3))) unsigned int*)l, 16, 0, 0);
}

// ---------------- prep: cvt X->bf16 + transpose-convert both W ----------------
__global__ void __launch_bounds__(256)
prep(const float* __restrict__ X, const float* __restrict__ Wqkv,
     const float* __restrict__ Wproj, ushort_t* __restrict__ Xb,
     ushort_t* __restrict__ WqkvT, ushort_t* __restrict__ WprojT) {
    __shared__ float tile[32][33];
    const int bid = blockIdx.x, tid = threadIdx.x;
    if (bid < 4096) {
        int i = (bid * 256 + tid) * 4;
        float4 v = *(const float4*)&X[i];
        ushort_t r[4] = { f2bf(v.x), f2bf(v.y), f2bf(v.z), f2bf(v.w) };
        *(uint2*)&Xb[i] = *(uint2*)r;
        return;
    }
    const float* W; ushort_t* Wt; int Nd, nb, kb;
    if (bid < 7168) {
        int b = bid - 4096; W = Wqkv;  Wt = WqkvT;  Nd = 3072;
        nb = (b % 96) * 32; kb = (b / 96) * 32;
    } else {
        int b = bid - 7168; W = Wproj; Wt = WprojT; Nd = 1024;
        nb = (b % 32) * 32; kb = (b / 32) * 32;
    }
    const int tx = tid & 31, ty = tid >> 5;
    for (int j = 0; j < 32; j += 8)
        tile[ty + j][tx] = W[(size_t)(kb + ty + j) * Nd + nb + tx];
    __syncthreads();
    for (int j = 0; j < 32; j += 8)
        Wt[(size_t)(nb + ty + j) * Dm + kb + tx] = f2bf(tile[tx][ty + j]);
}

// ---------------- QKV GEMM (BK=64, XCD-swizzled) ----------------
// cols [0,1024): *SCALE_LOG2E -> qkvB (Q); [1024,2048): -> qkvB (K);
// [2048,3072): transposed+key-permuted (pos = rotl2(token) per 64-window) to
// Vt via packed b128 stores.
__global__ void __launch_bounds__(256, 3)
gemm_qkv(const ushort_t* __restrict__ A, const ushort_t* __restrict__ Bt,
         const float* __restrict__ bias, ushort_t* __restrict__ Cq,
         ushort_t* __restrict__ Vt) {
    __shared__ alignas(16) ushort_t Alds[2][128 * 32];   // [kplane][row*32+cc*8]
    __shared__ alignas(16) ushort_t Blds[2][128 * 32];
    const int tid  = threadIdx.x;
    const int lane = tid & 63;
    const int w    = tid >> 6;
    const int quad = lane >> 4;
    const int l16  = lane & 15;
    // chunked XCD swizzle: 768 blocks, 96 consecutive per XCD.
    const int lin0 = blockIdx.y * 32 + blockIdx.x;
    const int lin  = (lin0 & 7) * 96 + (lin0 >> 3);
    const int mbase = (lin & 31) * 128;
    const int nbase = (lin >> 5) * 128;
    const int moff  = (w >> 1) * 64;
    const int noff  = (w & 1) * 64;
    const int K = Dm;

    f32x4 acc[4][4] = {};

    for (int kb = 0; kb < K; kb += 64) {
        __syncthreads();
        #pragma unroll
        for (int c = 0; c < 4; c++) {
            const int id    = c * 256 + w * 64 + lane;
            const int plane = id >> 9;           // wave-uniform (c>>1)
            const int rem   = id & 511;
            const int row   = rem >> 2, col = (rem & 3) * 8;
            ushort_t* dstA = &Alds[plane][(size_t)((c & 1) * 256 + w * 64) * 8];
            ushort_t* dstB = &Blds[plane][(size_t)((c & 1) * 256 + w * 64) * 8];
            gl2lds16(&A[(size_t)(mbase + row) * K + kb + plane * 32 + col], dstA);
            gl2lds16(&Bt[(size_t)(nbase + row) * K + kb + plane * 32 + col], dstB);
        }
        __syncthreads();
        #pragma unroll
        for (int kk = 0; kk < 2; kk++) {
            short8 a[4], b[4];
            #pragma unroll
            for (int m = 0; m < 4; m++)
                a[m] = *(const short8*)&Alds[kk][(moff + m * 16 + l16) * 32 + quad * 8];
            #pragma unroll
            for (int n = 0; n < 4; n++)
                b[n] = *(const short8*)&Blds[kk][(noff + n * 16 + l16) * 32 + quad * 8];
            #pragma unroll
            for (int m = 0; m < 4; m++)
                #pragma unroll
                for (int n = 0; n < 4; n++)
                    acc[m][n] = MFMA16(a[m], b[n], acc[m][n]);
        }
    }

    if (nbase < 2048) {
        const bool qscale = (nbase < 1024);
        #pragma unroll
        for (int m = 0; m < 4; m++)
            #pragma unroll
            for (int n = 0; n < 4; n++)
                #pragma unroll
                for (int r = 0; r < 4; r++) {
                    int row = mbase + moff + m * 16 + quad * 4 + r;
                    int col = nbase + noff + n * 16 + l16;
                    float v = acc[m][n][r] + bias[col];
                    if (qscale) v *= SCALE_LOG2E;
                    Cq[(size_t)row * D3 + col] = f2bf(v);
                }
    } else {
        // V block: token64 = m*16 + quad*4 + r -> pos = (quad*4+r)*4 + m.
        const int dbase = nbase - 2048 + noff;
        const size_t kb0 = (size_t)mbase + moff;   // 64-aligned key window
        #pragma unroll
        for (int n = 0; n < 4; n++) {
            const float bv = bias[nbase + noff + n * 16 + l16];
            ushort_t* vrow = Vt + (size_t)(dbase + n * 16 + l16) * Lq + kb0 + quad * 16;
            #pragma unroll
            for (int rp = 0; rp < 2; rp++) {
                ushort_t pk[8];
                #pragma unroll
                for (int dr = 0; dr < 2; dr++)
                    #pragma unroll
                    for (int m = 0; m < 4; m++)
                        pk[dr * 4 + m] = f2bf(acc[m][n][2 * rp + dr] + bv);
                *(short8*)(vrow + rp * 8) = *(const short8*)pk;
            }
        }
    }
}

// ---------------- flash attention (R21, unchanged) ----------------
// grid 256 = 16 pairs x 16 heads; head = bid & 15 (XCD pin); p = bid >> 4.
// block 1024 = 16 waves: sub = w&3 (32 q-rows), qtr = w>>2 (32 key-positions).
// sel 0: chunk p; sel 1: chunk 31-p => 33 rounds/block, uniform.
// Key permutation: QK chunk s out-row quad*4+r4 == PV-key quad*8+s*4+r4, so
// pP[m] is directly the K=32 PV B-fragment. True token of PV-key:
// tok = r4*16 + (qtr&1)*8 + quad*2 + s (for masking).
__global__ void __launch_bounds__(1024)
attn_fwd(const ushort_t* __restrict__ qkv, const ushort_t* __restrict__ Vt,
         ushort_t* __restrict__ O) {
    union SMem {
        struct { ushort_t K[2][2][64 * 64]; ushort_t V[2][2][64 * 64]; } kv;
        float Ml[3 * 256 * 35];             // 34 floats/thread, pitch 35
    };
    __shared__ SMem sm;

    const int tid  = threadIdx.x;
    const int lane = tid & 63;
    const int w    = tid >> 6;          // [0,16)
    const int qtr  = w >> 2;            // key quarter [0,4)
    const int sub  = w & 3;             // q sub-chunk (32 rows)
    const int quad = lane >> 4;
    const int l16  = lane & 15;
    const int bid  = blockIdx.x;
    const int h    = bid & 15;
    const int p    = bid >> 4;          // [0,16)
    const float NEG_INF = -__builtin_inff();

    const ushort_t* kbase = qkv + Dm + h * HD;           // K rows, stride D3
    const ushort_t* vbase = Vt + (size_t)h * HD * Lq;    // V^T rows, stride Lq

    // K fragment: A-row i (=l16) of chunk s holds token
    //   tok = (i&3)*16 + (qtr&1)*8 + ((i>>2)&3)*2 + s
    // Read slot fk matches staging swizzle g'(tok) = ((tok>>4)&3)*2+((tok>>1)&1).
    int koff[2][2];
    #pragma unroll
    for (int s = 0; s < 2; s++) {
        const int tok = (l16 & 3) * 16 + (qtr & 1) * 8 + ((l16 >> 2) & 3) * 2 + s;
        const int fk  = ((l16 & 3) << 1) | ((l16 >> 2) & 1);
        #pragma unroll
        for (int kh = 0; kh < 2; kh++)
            koff[s][kh] = tok * 64 + (((kh * 4 + quad) ^ fk) * 8);
    }
    // V fragment (K=32 A-frag): row = t4*16+l16 (d), keys = contiguous 8
    // positions (qtr&1)*32 + quad*8..+7 -> one b128 per t4.
    int voff[4];
    #pragma unroll
    for (int t4 = 0; t4 < 4; t4++) {
        const int row = t4 * 16 + l16;
        voff[t4] = row * 64 + (((((qtr & 1) * 4) + quad) ^ (row & 7)) * 8);
    }
    // true-token base for masking: r*128 + kmc2 + s + r4*16
    const int kmc2 = (qtr >> 1) * 64 + (qtr & 1) * 8 + quad * 2;

    // staging: waves 0-7 stage K (both 64-tiles), waves 8-15 stage V.
    const int  tv  = tid & 511;
    const int  rr  = tv >> 3;
    const int  ccK = (tv & 7) ^ ((((rr >> 4) & 3) << 1) | ((rr >> 1) & 1));
    const int  ccV = (tv & 7) ^ (rr & 7);
    const bool isK = (tid < 512);
    const int  dsto = (w & 7) * 512;
    const ushort_t* kse = kbase + (size_t)rr * D3 + ccK * 8;
    const ushort_t* vse = vbase + (size_t)rr * Lq + ccV * 8;

    for (int sel = 0; sel < 2; sel++) {
        const int c      = sel ? (31 - p) : p;
        const int qc     = c * 128;
        const int rounds = c + 1;
        const int qrow0  = qc + sub * 32;

        short8 qf[2][2];
        #pragma unroll
        for (int m = 0; m < 2; m++) {
            const ushort_t* qr = qkv + (size_t)(qrow0 + m * 16 + l16) * D3 + h * HD;
            qf[m][0] = *(const short8*)(qr + quad * 8);
            qf[m][1] = *(const short8*)(qr + 32 + quad * 8);
        }

        f32x4 o[2][4] = {};
        float sacc[2] = { 0.f, 0.f };

        const ushort_t* kp = kse;
        const ushort_t* vp = vse;

        auto stage = [&](int b) {
            if (isK) {
                gl2lds16(kp,           &sm.kv.K[0][b][dsto]);
                gl2lds16(kp + 64 * D3, &sm.kv.K[1][b][dsto]);
            } else {
                gl2lds16(vp,           &sm.kv.V[0][b][dsto]);
                gl2lds16(vp + 64,      &sm.kv.V[1][b][dsto]);
            }
            kp += (size_t)128 * D3;
            vp += 128;
        };

        stage(0);

        for (int r = 0; r < rounds; r++) {
            const int buf = r & 1;
            __syncthreads();
            if (r + 1 < rounds) stage(buf ^ 1);

            const ushort_t* Kb = &sm.kv.K[qtr >> 1][buf][0];
            const ushort_t* Vb = &sm.kv.V[qtr >> 1][buf][0];
            const bool domask = (r == rounds - 1);
            const int qg0 = qrow0 + l16;

            // K fragments, then QK for m=0
            short8 kf[2][2];
            #pragma unroll
            for (int s = 0; s < 2; s++)
                #pragma unroll
                for (int kh = 0; kh < 2; kh++)
                    kf[s][kh] = *(const short8*)&Kb[koff[s][kh]];

            f32x4 st0[2], st1[2];
            #pragma unroll
            for (int s = 0; s < 2; s++) {
                f32x4 t = {};
                t = MFMA16(kf[s][0], qf[0][0], t);
                t = MFMA16(kf[s][1], qf[0][1], t);
                st0[s] = t;
            }

            // V fragments issue under QK[m0]'s shadow; then QK for m=1
            short8 vf[4];
            #pragma unroll
            for (int t4 = 0; t4 < 4; t4++)
                vf[t4] = *(const short8*)&Vb[voff[t4]];

            #pragma unroll
            for (int s = 0; s < 2; s++) {
                f32x4 t = {};
                t = MFMA16(kf[s][0], qf[1][0], t);
                t = MFMA16(kf[s][1], qf[1][1], t);
                st1[s] = t;
            }

            // exp2 + pack m0 (VALU; overlaps QK[m1] MFMA)
            short8 pP0;
            {
                union { unsigned int u4[4]; short8 s8; } pb;
                #pragma unroll
                for (int s = 0; s < 2; s++) {
                    float e[4];
                    #pragma unroll
                    for (int r4 = 0; r4 < 4; r4++) {
                        float v = st0[s][r4];
                        if (domask && (r * 128 + kmc2 + s + r4 * 16 > qg0))
                            v = NEG_INF;
                        e[r4] = __builtin_amdgcn_exp2f(v);
                    }
                    sacc[0] += (e[0] + e[1]) + (e[2] + e[3]);
                    pb.u4[s * 2]     = cvtpk(e[0], e[1]);
                    pb.u4[s * 2 + 1] = cvtpk(e[2], e[3]);
                }
                pP0 = pb.s8;
            }

            // PV m0 (MFMA; overlaps exp2 m1 below)
            #pragma unroll
            for (int t4 = 0; t4 < 4; t4++)
                o[0][t4] = MFMA16(vf[t4], pP0, o[0][t4]);

            // exp2 + pack m1
            short8 pP1;
            {
                union { unsigned int u4[4]; short8 s8; } pb;
                #pragma unroll
                for (int s = 0; s < 2; s++) {
                    float e[4];
                    #pragma unroll
                    for (int r4 = 0; r4 < 4; r4++) {
                        float v = st1[s][r4];
                        if (domask && (r * 128 + kmc2 + s + r4 * 16 > qg0 + 16))
                            v = NEG_INF;
                        e[r4] = __builtin_amdgcn_exp2f(v);
                    }
                    sacc[1] += (e[0] + e[1]) + (e[2] + e[3]);
                    pb.u4[s * 2]     = cvtpk(e[0], e[1]);
                    pb.u4[s * 2 + 1] = cvtpk(e[2], e[3]);
                }
                pP1 = pb.s8;
            }

            // PV m1
            #pragma unroll
            for (int t4 = 0; t4 < 4; t4++)
                o[1][t4] = MFMA16(vf[t4], pP1, o[1][t4]);
        }

        // reduce sacc across quads (keys of this quarter fully summed)
        #pragma unroll
        for (int m = 0; m < 2; m++) {
            sacc[m] += __shfl_xor(sacc[m], 16);
            sacc[m] += __shfl_xor(sacc[m], 32);
        }

        // 4-way merge through Ml (aliases K/V LDS; rounds done, barriers
        // separate all uses).
        __syncthreads();
        if (qtr != 0) {
            float* dst = sm.Ml + (size_t)((qtr - 1) * 256 + sub * 64 + lane) * 35;
            #pragma unroll
            for (int m = 0; m < 2; m++)
                #pragma unroll
                for (int t4 = 0; t4 < 4; t4++)
                    *(f32x4*)(dst + (m * 4 + t4) * 4) = o[m][t4];
            dst[32] = sacc[0];
            dst[33] = sacc[1];
        }
        __syncthreads();
        if (qtr == 0) {
            #pragma unroll
            for (int j = 0; j < 3; j++) {
                const float* src = sm.Ml + (size_t)(j * 256 + sub * 64 + lane) * 35;
                #pragma unroll
                for (int m = 0; m < 2; m++)
                    #pragma unroll
                    for (int t4 = 0; t4 < 4; t4++)
                        o[m][t4] += *(const f32x4*)(src + (m * 4 + t4) * 4);
                sacc[0] += src[32];
                sacc[1] += src[33];
            }
            #pragma unroll
            for (int m = 0; m < 2; m++) {
                const float inv = 1.0f / sacc[m];
                ushort_t* orow = O + (size_t)(qrow0 + m * 16 + l16) * Dm + h * HD;
                #pragma unroll
                for (int t4 = 0; t4 < 4; t4++) {
                    ushort_t pk[4];
                    #pragma unroll
                    for (int r4 = 0; r4 < 4; r4++)
                        pk[r4] = f2bf(o[m][t4][r4] * inv);
                    *(uint2*)(orow + t4 * 16 + quad * 4) = *(const uint2*)pk;
                }
            }
        }
        __syncthreads();
    }
}

// ---------------- proj GEMM: 128x128 tiles, BK=64, XCD-swizzled -------------
// 256 blocks = 1/CU; same loop structure as gemm_qkv, f32 epilogue.
__global__ void __launch_bounds__(256, 3)
gemm_proj(const ushort_t* __restrict__ A, const ushort_t* __restrict__ Bt,
          const float* __restrict__ bias, float* __restrict__ C) {
    __shared__ alignas(16) ushort_t Alds[2][128 * 32];
    __shared__ alignas(16) ushort_t Blds[2][128 * 32];
    const int tid  = threadIdx.x;
    const int lane = tid & 63;
    const int w    = tid >> 6;
    const int quad = lane >> 4;
    const int l16  = lane & 15;
    // chunked XCD swizzle: 256 blocks, 32 consecutive per XCD.
    const int lin0 = blockIdx.y * 32 + blockIdx.x;
    const int lin  = (lin0 & 7) * 32 + (lin0 >> 3);
    const int mbase = (lin & 31) * 128;
    const int nbase = (lin >> 5) * 128;
    const int moff  = (w >> 1) * 64;
    const int noff  = (w & 1) * 64;
    const int K = Dm, N = Dm;

    f32x4 acc[4][4] = {};

    for (int kb = 0; kb < K; kb += 64) {
        __syncthreads();
        #pragma unroll
        for (int c = 0; c < 4; c++) {
            const int id    = c * 256 + w * 64 + lane;
            const int plane = id >> 9;           // wave-uniform (c>>1)
            const int rem   = id & 511;
            const int row   = rem >> 2, col = (rem & 3) * 8;
            ushort_t* dstA = &Alds[plane][(size_t)((c & 1) * 256 + w * 64) * 8];
            ushort_t* dstB = &Blds[plane][(size_t)((c & 1) * 256 + w * 64) * 8];
            gl2lds16(&A[(size_t)(mbase + row) * K + kb + plane * 32 + col], dstA);
            gl2lds16(&Bt[(size_t)(nbase + row) * K + kb + plane * 32 + col], dstB);
        }
        __syncthreads();
        #pragma unroll
        for (int kk = 0; kk < 2; kk++) {
            short8 a[4], b[4];
            #pragma unroll
            for (int m = 0; m < 4; m++)
                a[m] = *(const short8*)&Alds[kk][(moff + m * 16 + l16) * 32 + quad * 8];
            #pragma unroll
            for (int n = 0; n < 4; n++)
                b[n] = *(const short8*)&Blds[kk][(noff + n * 16 + l16) * 32 + quad * 8];
            #pragma unroll
            for (int m = 0; m < 4; m++)
                #pragma unroll
                for (int n = 0; n < 4; n++)
                    acc[m][n] = MFMA16(a[m], b[n], acc[m][n]);
        }
    }

    #pragma unroll
    for (int m = 0; m < 4; m++)
        #pragma unroll
        for (int n = 0; n < 4; n++)
            #pragma unroll
            for (int r = 0; r < 4; r++) {
                int row = mbase + moff + m * 16 + quad * 4 + r;
                int col = nbase + noff + n * 16 + l16;
                C[(size_t)row * N + col] = acc[m][n][r] + bias[col];
            }
}

// ---------------- launch ----------------
extern "C" void kernel_launch(void* const* d_in, const int* in_sizes, int n_in,
                              void* d_out, int out_size, void* d_ws, size_t ws_size,
                              hipStream_t stream) {
    const float* X     = (const float*)d_in[0];
    const float* Wqkv  = (const float*)d_in[1];
    const float* bqkv  = (const float*)d_in[2];
    const float* Wproj = (const float*)d_in[3];
    const float* bproj = (const float*)d_in[4];
    float* out = (float*)d_out;

    ushort_t* ws     = (ushort_t*)d_ws;
    ushort_t* Xb     = ws;                               // 4096x1024
    ushort_t* WqkvT  = Xb + (size_t)Lq * Dm;             // 3072x1024
    ushort_t* WprojT = WqkvT + (size_t)D3 * Dm;          // 1024x1024
    ushort_t* qkvB   = WprojT + (size_t)Dm * Dm;         // 4096x3072 (Q,K used)
    ushort_t* VtB    = qkvB + (size_t)Lq * D3;           // 16x64x4096
    ushort_t* Ob     = VtB + (size_t)NH * HD * Lq;       // 4096x1024

    prep<<<dim3(8192), 256, 0, stream>>>(X, Wqkv, Wproj, Xb, WqkvT, WprojT);

    gemm_qkv<<<dim3(Lq / 128, D3 / 128), 256, 0, stream>>>(
        Xb, WqkvT, bqkv, qkvB, VtB);

    attn_fwd<<<dim3(256), 1024, 0, stream>>>(qkvB, VtB, Ob);

    gemm_proj<<<dim3(Lq / 128, Dm / 128), 256, 0, stream>>>(
        Ob, WprojT, bproj, out);
}

// Round 14
// 190.245 us; speedup vs baseline: 1.0271x; 1.0140x over previous
//
#include <hip/hip_runtime.h>
#include <hip/hip_bf16.h>
#include <string.h>

// MultiHeadAttention: B=1, L=4096, D=1024, H=16, HD=64, causal.
// R26 = R21 byte-exact (consolidation to best verified config, 191.6us):
//  - R25's proj 128x128 was neutral-to-negative (192.9) -> reverted to 128x64.
//  - attn: R19 geometry + m-slice software pipeline (QK[m0] -> vf+QK[m1] ->
//    exp2[m0]+PV[m0] -> exp2[m1]+PV[m1]); K=32 PV via position-space key
//    permutation; in-register softmax; no setprio (measured faster without).
//  - gemm_qkv: BK=64 kk-split, XCD-swizzled, 3 blocks/CU.
//  - Session plateau: attn is latency-bound (MfmaUtil 22 + VALUBusy 35, HBM
//    4%); all verified-safe levers spent; deeper pipelines raced 3x blind.

typedef unsigned short ushort_t;
typedef __attribute__((ext_vector_type(8))) short short8;
typedef __attribute__((ext_vector_type(4))) float f32x4;

#define MFMA16(a, b, c) __builtin_amdgcn_mfma_f32_16x16x32_bf16(a, b, c, 0, 0, 0)

static constexpr int Lq = 4096;
static constexpr int Dm = 1024;
static constexpr int NH = 16;
static constexpr int HD = 64;
static constexpr int D3 = 3072;
static constexpr float SCALE_LOG2E = 0.125f * 1.44269504088896340736f;

__device__ __forceinline__ ushort_t f2bf(float f) {
    union { float f; unsigned int u; } x{f};
    unsigned int u = x.u;
    u += 0x7fffu + ((u >> 16) & 1u);   // RNE
    return (ushort_t)(u >> 16);
}

// packed fp32x2 -> bf16x2, hardware RNE (lo = a, hi = b)
__device__ __forceinline__ unsigned int cvtpk(float a, float b) {
    unsigned int r;
    asm("v_cvt_pk_bf16_f32 %0, %1, %2" : "=v"(r) : "v"(a), "v"(b));
    return r;
}

__device__ __forceinline__ void gl2lds16(const ushort_t* g, ushort_t* l) {
    __builtin_amdgcn_global_load_lds(
        (const __attribute__((address_space(1))) unsigned int*)g,
        (__attribute__((address_space(3))) unsigned int*)l, 16, 0, 0);
}

// ---------------- prep: cvt X->bf16 + transpose-convert both W ----------------
__global__ void __launch_bounds__(256)
prep(const float* __restrict__ X, const float* __restrict__ Wqkv,
     const float* __restrict__ Wproj, ushort_t* __restrict__ Xb,
     ushort_t* __restrict__ WqkvT, ushort_t* __restrict__ WprojT) {
    __shared__ float tile[32][33];
    const int bid = blockIdx.x, tid = threadIdx.x;
    if (bid < 4096) {
        int i = (bid * 256 + tid) * 4;
        float4 v = *(const float4*)&X[i];
        ushort_t r[4] = { f2bf(v.x), f2bf(v.y), f2bf(v.z), f2bf(v.w) };
        *(uint2*)&Xb[i] = *(uint2*)r;
        return;
    }
    const float* W; ushort_t* Wt; int Nd, nb, kb;
    if (bid < 7168) {
        int b = bid - 4096; W = Wqkv;  Wt = WqkvT;  Nd = 3072;
        nb = (b % 96) * 32; kb = (b / 96) * 32;
    } else {
        int b = bid - 7168; W = Wproj; Wt = WprojT; Nd = 1024;
        nb = (b % 32) * 32; kb = (b / 32) * 32;
    }
    const int tx = tid & 31, ty = tid >> 5;
    for (int j = 0; j < 32; j += 8)
        tile[ty + j][tx] = W[(size_t)(kb + ty + j) * Nd + nb + tx];
    __syncthreads();
    for (int j = 0; j < 32; j += 8)
        Wt[(size_t)(nb + ty + j) * Dm + kb + tx] = f2bf(tile[tx][ty + j]);
}

// ---------------- QKV GEMM (BK=64, XCD-swizzled) ----------------
// cols [0,1024): *SCALE_LOG2E -> qkvB (Q); [1024,2048): -> qkvB (K);
// [2048,3072): transposed+key-permuted (pos = rotl2(token) per 64-window) to
// Vt via packed b128 stores.
__global__ void __launch_bounds__(256, 3)
gemm_qkv(const ushort_t* __restrict__ A, const ushort_t* __restrict__ Bt,
         const float* __restrict__ bias, ushort_t* __restrict__ Cq,
         ushort_t* __restrict__ Vt) {
    __shared__ alignas(16) ushort_t Alds[2][128 * 32];   // [kplane][row*32+cc*8]
    __shared__ alignas(16) ushort_t Blds[2][128 * 32];
    const int tid  = threadIdx.x;
    const int lane = tid & 63;
    const int w    = tid >> 6;
    const int quad = lane >> 4;
    const int l16  = lane & 15;
    // chunked XCD swizzle: 768 blocks, 96 consecutive per XCD.
    const int lin0 = blockIdx.y * 32 + blockIdx.x;
    const int lin  = (lin0 & 7) * 96 + (lin0 >> 3);
    const int mbase = (lin & 31) * 128;
    const int nbase = (lin >> 5) * 128;
    const int moff  = (w >> 1) * 64;
    const int noff  = (w & 1) * 64;
    const int K = Dm;

    f32x4 acc[4][4] = {};

    for (int kb = 0; kb < K; kb += 64) {
        __syncthreads();
        #pragma unroll
        for (int c = 0; c < 4; c++) {
            const int id    = c * 256 + w * 64 + lane;
            const int plane = id >> 9;           // wave-uniform (c>>1)
            const int rem   = id & 511;
            const int row   = rem >> 2, col = (rem & 3) * 8;
            ushort_t* dstA = &Alds[plane][(size_t)((c & 1) * 256 + w * 64) * 8];
            ushort_t* dstB = &Blds[plane][(size_t)((c & 1) * 256 + w * 64) * 8];
            gl2lds16(&A[(size_t)(mbase + row) * K + kb + plane * 32 + col], dstA);
            gl2lds16(&Bt[(size_t)(nbase + row) * K + kb + plane * 32 + col], dstB);
        }
        __syncthreads();
        #pragma unroll
        for (int kk = 0; kk < 2; kk++) {
            short8 a[4], b[4];
            #pragma unroll
            for (int m = 0; m < 4; m++)
                a[m] = *(const short8*)&Alds[kk][(moff + m * 16 + l16) * 32 + quad * 8];
            #pragma unroll
            for (int n = 0; n < 4; n++)
                b[n] = *(const short8*)&Blds[kk][(noff + n * 16 + l16) * 32 + quad * 8];
            #pragma unroll
            for (int m = 0; m < 4; m++)
                #pragma unroll
                for (int n = 0; n < 4; n++)
                    acc[m][n] = MFMA16(a[m], b[n], acc[m][n]);
        }
    }

    if (nbase < 2048) {
        const bool qscale = (nbase < 1024);
        #pragma unroll
        for (int m = 0; m < 4; m++)
            #pragma unroll
            for (int n = 0; n < 4; n++)
                #pragma unroll
                for (int r = 0; r < 4; r++) {
                    int row = mbase + moff + m * 16 + quad * 4 + r;
                    int col = nbase + noff + n * 16 + l16;
                    float v = acc[m][n][r] + bias[col];
                    if (qscale) v *= SCALE_LOG2E;
                    Cq[(size_t)row * D3 + col] = f2bf(v);
                }
    } else {
        // V block: token64 = m*16 + quad*4 + r -> pos = (quad*4+r)*4 + m.
        const int dbase = nbase - 2048 + noff;
        const size_t kb0 = (size_t)mbase + moff;   // 64-aligned key window
        #pragma unroll
        for (int n = 0; n < 4; n++) {
            const float bv = bias[nbase + noff + n * 16 + l16];
            ushort_t* vrow = Vt + (size_t)(dbase + n * 16 + l16) * Lq + kb0 + quad * 16;
            #pragma unroll
            for (int rp = 0; rp < 2; rp++) {
                ushort_t pk[8];
                #pragma unroll
                for (int dr = 0; dr < 2; dr++)
                    #pragma unroll
                    for (int m = 0; m < 4; m++)
                        pk[dr * 4 + m] = f2bf(acc[m][n][2 * rp + dr] + bv);
                *(short8*)(vrow + rp * 8) = *(const short8*)pk;
            }
        }
    }
}

// ---------------- flash attention (R21, unchanged) ----------------
// grid 256 = 16 pairs x 16 heads; head = bid & 15 (XCD pin); p = bid >> 4.
// block 1024 = 16 waves: sub = w&3 (32 q-rows), qtr = w>>2 (32 key-positions).
// sel 0: chunk p; sel 1: chunk 31-p => 33 rounds/block, uniform.
// Key permutation: QK chunk s out-row quad*4+r4 == PV-key quad*8+s*4+r4, so
// pP[m] is directly the K=32 PV B-fragment. True token of PV-key:
// tok = r4*16 + (qtr&1)*8 + quad*2 + s (for masking).
__global__ void __launch_bounds__(1024)
attn_fwd(const ushort_t* __restrict__ qkv, const ushort_t* __restrict__ Vt,
         ushort_t* __restrict__ O) {
    union SMem {
        struct { ushort_t K[2][2][64 * 64]; ushort_t V[2][2][64 * 64]; } kv;
        float Ml[3 * 256 * 35];             // 34 floats/thread, pitch 35
    };
    __shared__ SMem sm;

    const int tid  = threadIdx.x;
    const int lane = tid & 63;
    const int w    = tid >> 6;          // [0,16)
    const int qtr  = w >> 2;            // key quarter [0,4)
    const int sub  = w & 3;             // q sub-chunk (32 rows)
    const int quad = lane >> 4;
    const int l16  = lane & 15;
    const int bid  = blockIdx.x;
    const int h    = bid & 15;
    const int p    = bid >> 4;          // [0,16)
    const float NEG_INF = -__builtin_inff();

    const ushort_t* kbase = qkv + Dm + h * HD;           // K rows, stride D3
    const ushort_t* vbase = Vt + (size_t)h * HD * Lq;    // V^T rows, stride Lq

    // K fragment: A-row i (=l16) of chunk s holds token
    //   tok = (i&3)*16 + (qtr&1)*8 + ((i>>2)&3)*2 + s
    // Read slot fk matches staging swizzle g'(tok) = ((tok>>4)&3)*2+((tok>>1)&1).
    int koff[2][2];
    #pragma unroll
    for (int s = 0; s < 2; s++) {
        const int tok = (l16 & 3) * 16 + (qtr & 1) * 8 + ((l16 >> 2) & 3) * 2 + s;
        const int fk  = ((l16 & 3) << 1) | ((l16 >> 2) & 1);
        #pragma unroll
        for (int kh = 0; kh < 2; kh++)
            koff[s][kh] = tok * 64 + (((kh * 4 + quad) ^ fk) * 8);
    }
    // V fragment (K=32 A-frag): row = t4*16+l16 (d), keys = contiguous 8
    // positions (qtr&1)*32 + quad*8..+7 -> one b128 per t4.
    int voff[4];
    #pragma unroll
    for (int t4 = 0; t4 < 4; t4++) {
        const int row = t4 * 16 + l16;
        voff[t4] = row * 64 + (((((qtr & 1) * 4) + quad) ^ (row & 7)) * 8);
    }
    // true-token base for masking: r*128 + kmc2 + s + r4*16
    const int kmc2 = (qtr >> 1) * 64 + (qtr & 1) * 8 + quad * 2;

    // staging: waves 0-7 stage K (both 64-tiles), waves 8-15 stage V.
    const int  tv  = tid & 511;
    const int  rr  = tv >> 3;
    const int  ccK = (tv & 7) ^ ((((rr >> 4) & 3) << 1) | ((rr >> 1) & 1));
    const int  ccV = (tv & 7) ^ (rr & 7);
    const bool isK = (tid < 512);
    const int  dsto = (w & 7) * 512;
    const ushort_t* kse = kbase + (size_t)rr * D3 + ccK * 8;
    const ushort_t* vse = vbase + (size_t)rr * Lq + ccV * 8;

    for (int sel = 0; sel < 2; sel++) {
        const int c      = sel ? (31 - p) : p;
        const int qc     = c * 128;
        const int rounds = c + 1;
        const int qrow0  = qc + sub * 32;

        short8 qf[2][2];
        #pragma unroll
        for (int m = 0; m < 2; m++) {
            const ushort_t* qr = qkv + (size_t)(qrow0 + m * 16 + l16) * D3 + h * HD;
            qf[m][0] = *(const short8*)(qr + quad * 8);
            qf[m][1] = *(const short8*)(qr + 32 + quad * 8);
        }

        f32x4 o[2][4] = {};
        float sacc[2] = { 0.f, 0.f };

        const ushort_t* kp = kse;
        const ushort_t* vp = vse;

        auto stage = [&](int b) {
            if (isK) {
                gl2lds16(kp,           &sm.kv.K[0][b][dsto]);
                gl2lds16(kp + 64 * D3, &sm.kv.K[1][b][dsto]);
            } else {
                gl2lds16(vp,           &sm.kv.V[0][b][dsto]);
                gl2lds16(vp + 64,      &sm.kv.V[1][b][dsto]);
            }
            kp += (size_t)128 * D3;
            vp += 128;
        };

        stage(0);

        for (int r = 0; r < rounds; r++) {
            const int buf = r & 1;
            __syncthreads();
            if (r + 1 < rounds) stage(buf ^ 1);

            const ushort_t* Kb = &sm.kv.K[qtr >> 1][buf][0];
            const ushort_t* Vb = &sm.kv.V[qtr >> 1][buf][0];
            const bool domask = (r == rounds - 1);
            const int qg0 = qrow0 + l16;

            // K fragments, then QK for m=0
            short8 kf[2][2];
            #pragma unroll
            for (int s = 0; s < 2; s++)
                #pragma unroll
                for (int kh = 0; kh < 2; kh++)
                    kf[s][kh] = *(const short8*)&Kb[koff[s][kh]];

            f32x4 st0[2], st1[2];
            #pragma unroll
            for (int s = 0; s < 2; s++) {
                f32x4 t = {};
                t = MFMA16(kf[s][0], qf[0][0], t);
                t = MFMA16(kf[s][1], qf[0][1], t);
                st0[s] = t;
            }

            // V fragments issue under QK[m0]'s shadow; then QK for m=1
            short8 vf[4];
            #pragma unroll
            for (int t4 = 0; t4 < 4; t4++)
                vf[t4] = *(const short8*)&Vb[voff[t4]];

            #pragma unroll
            for (int s = 0; s < 2; s++) {
                f32x4 t = {};
                t = MFMA16(kf[s][0], qf[1][0], t);
                t = MFMA16(kf[s][1], qf[1][1], t);
                st1[s] = t;
            }

            // exp2 + pack m0 (VALU; overlaps QK[m1] MFMA)
            short8 pP0;
            {
                union { unsigned int u4[4]; short8 s8; } pb;
                #pragma unroll
                for (int s = 0; s < 2; s++) {
                    float e[4];
                    #pragma unroll
                    for (int r4 = 0; r4 < 4; r4++) {
                        float v = st0[s][r4];
                        if (domask && (r * 128 + kmc2 + s + r4 * 16 > qg0))
                            v = NEG_INF;
                        e[r4] = __builtin_amdgcn_exp2f(v);
                    }
                    sacc[0] += (e[0] + e[1]) + (e[2] + e[3]);
                    pb.u4[s * 2]     = cvtpk(e[0], e[1]);
                    pb.u4[s * 2 + 1] = cvtpk(e[2], e[3]);
                }
                pP0 = pb.s8;
            }

            // PV m0 (MFMA; overlaps exp2 m1 below)
            #pragma unroll
            for (int t4 = 0; t4 < 4; t4++)
                o[0][t4] = MFMA16(vf[t4], pP0, o[0][t4]);

            // exp2 + pack m1
            short8 pP1;
            {
                union { unsigned int u4[4]; short8 s8; } pb;
                #pragma unroll
                for (int s = 0; s < 2; s++) {
                    float e[4];
                    #pragma unroll
                    for (int r4 = 0; r4 < 4; r4++) {
                        float v = st1[s][r4];
                        if (domask && (r * 128 + kmc2 + s + r4 * 16 > qg0 + 16))
                            v = NEG_INF;
                        e[r4] = __builtin_amdgcn_exp2f(v);
                    }
                    sacc[1] += (e[0] + e[1]) + (e[2] + e[3]);
                    pb.u4[s * 2]     = cvtpk(e[0], e[1]);
                    pb.u4[s * 2 + 1] = cvtpk(e[2], e[3]);
                }
                pP1 = pb.s8;
            }

            // PV m1
            #pragma unroll
            for (int t4 = 0; t4 < 4; t4++)
                o[1][t4] = MFMA16(vf[t4], pP1, o[1][t4]);
        }

        // reduce sacc across quads (keys of this quarter fully summed)
        #pragma unroll
        for (int m = 0; m < 2; m++) {
            sacc[m] += __shfl_xor(sacc[m], 16);
            sacc[m] += __shfl_xor(sacc[m], 32);
        }

        // 4-way merge through Ml (aliases K/V LDS; rounds done, barriers
        // separate all uses).
        __syncthreads();
        if (qtr != 0) {
            float* dst = sm.Ml + (size_t)((qtr - 1) * 256 + sub * 64 + lane) * 35;
            #pragma unroll
            for (int m = 0; m < 2; m++)
                #pragma unroll
                for (int t4 = 0; t4 < 4; t4++)
                    *(f32x4*)(dst + (m * 4 + t4) * 4) = o[m][t4];
            dst[32] = sacc[0];
            dst[33] = sacc[1];
        }
        __syncthreads();
        if (qtr == 0) {
            #pragma unroll
            for (int j = 0; j < 3; j++) {
                const float* src = sm.Ml + (size_t)(j * 256 + sub * 64 + lane) * 35;
                #pragma unroll
                for (int m = 0; m < 2; m++)
                    #pragma unroll
                    for (int t4 = 0; t4 < 4; t4++)
                        o[m][t4] += *(const f32x4*)(src + (m * 4 + t4) * 4);
                sacc[0] += src[32];
                sacc[1] += src[33];
            }
            #pragma unroll
            for (int m = 0; m < 2; m++) {
                const float inv = 1.0f / sacc[m];
                ushort_t* orow = O + (size_t)(qrow0 + m * 16 + l16) * Dm + h * HD;
                #pragma unroll
                for (int t4 = 0; t4 < 4; t4++) {
                    ushort_t pk[4];
                    #pragma unroll
                    for (int r4 = 0; r4 < 4; r4++)
                        pk[r4] = f2bf(o[m][t4][r4] * inv);
                    *(uint2*)(orow + t4 * 16 + quad * 4) = *(const uint2*)pk;
                }
            }
        }
        __syncthreads();
    }
}

// ---------------- proj GEMM: 128x64 tiles, BK=64, XCD-swizzled ----------------
__global__ void __launch_bounds__(256, 2)
gemm_proj(const ushort_t* __restrict__ A, const ushort_t* __restrict__ Bt,
          const float* __restrict__ bias, float* __restrict__ C) {
    __shared__ alignas(16) ushort_t Alds[2][128 * 32];
    __shared__ alignas(16) ushort_t Blds[2][64 * 32];
    const int tid  = threadIdx.x;
    const int lane = tid & 63;
    const int w    = tid >> 6;
    const int quad = lane >> 4;
    const int l16  = lane & 15;
    // chunked XCD swizzle: 512 blocks, 64 consecutive per XCD.
    const int lin0 = blockIdx.y * 32 + blockIdx.x;
    const int lin  = (lin0 & 7) * 64 + (lin0 >> 3);
    const int mbase = (lin & 31) * 128;
    const int nbase = (lin >> 5) * 64;
    const int moff  = (w >> 1) * 64;
    const int noff  = (w & 1) * 32;
    const int K = Dm, N = Dm;

    f32x4 acc[4][2] = {};

    for (int kb = 0; kb < K; kb += 64) {
        __syncthreads();
        #pragma unroll
        for (int c = 0; c < 4; c++) {
            const int id    = c * 256 + w * 64 + lane;
            const int plane = id >> 9;
            const int rem   = id & 511;
            const int row   = rem >> 2, col = (rem & 3) * 8;
            gl2lds16(&A[(size_t)(mbase + row) * K + kb + plane * 32 + col],
                     &Alds[plane][(size_t)((c & 1) * 256 + w * 64) * 8]);
        }
        #pragma unroll
        for (int c = 0; c < 2; c++) {
            const int id    = c * 256 + w * 64 + lane;
            const int plane = id >> 8;
            const int rem   = id & 255;
            const int row   = rem >> 2, col = (rem & 3) * 8;
            gl2lds16(&Bt[(size_t)(nbase + row) * K + kb + plane * 32 + col],
                     &Blds[plane][(size_t)(w * 64) * 8]);
        }
        __syncthreads();
        #pragma unroll
        for (int kk = 0; kk < 2; kk++) {
            short8 a[4], b[2];
            #pragma unroll
            for (int m = 0; m < 4; m++)
                a[m] = *(const short8*)&Alds[kk][(moff + m * 16 + l16) * 32 + quad * 8];
            #pragma unroll
            for (int n = 0; n < 2; n++)
                b[n] = *(const short8*)&Blds[kk][(noff + n * 16 + l16) * 32 + quad * 8];
            #pragma unroll
            for (int m = 0; m < 4; m++)
                #pragma unroll
                for (int n = 0; n < 2; n++)
                    acc[m][n] = MFMA16(a[m], b[n], acc[m][n]);
        }
    }

    #pragma unroll
    for (int m = 0; m < 4; m++)
        #pragma unroll
        for (int n = 0; n < 2; n++)
            #pragma unroll
            for (int r = 0; r < 4; r++) {
                int row = mbase + moff + m * 16 + quad * 4 + r;
                int col = nbase + noff + n * 16 + l16;
                C[(size_t)row * N + col] = acc[m][n][r] + bias[col];
            }
}

// ---------------- launch ----------------
extern "C" void kernel_launch(void* const* d_in, const int* in_sizes, int n_in,
                              void* d_out, int out_size, void* d_ws, size_t ws_size,
                              hipStream_t stream) {
    const float* X     = (const float*)d_in[0];
    const float* Wqkv  = (const float*)d_in[1];
    const float* bqkv  = (const float*)d_in[2];
    const float* Wproj = (const float*)d_in[3];
    const float* bproj = (const float*)d_in[4];
    float* out = (float*)d_out;

    ushort_t* ws     = (ushort_t*)d_ws;
    ushort_t* Xb     = ws;                               // 4096x1024
    ushort_t* WqkvT  = Xb + (size_t)Lq * Dm;             // 3072x1024
    ushort_t* WprojT = WqkvT + (size_t)D3 * Dm;          // 1024x1024
    ushort_t* qkvB   = WprojT + (size_t)Dm * Dm;         // 4096x3072 (Q,K used)
    ushort_t* VtB    = qkvB + (size_t)Lq * D3;           // 16x64x4096
    ushort_t* Ob     = VtB + (size_t)NH * HD * Lq;       // 4096x1024

    prep<<<dim3(8192), 256, 0, stream>>>(X, Wqkv, Wproj, Xb, WqkvT, WprojT);

    gemm_qkv<<<dim3(Lq / 128, D3 / 128), 256, 0, stream>>>(
        Xb, WqkvT, bqkv, qkvB, VtB);

    attn_fwd<<<dim3(256), 1024, 0, stream>>>(qkvB, VtB, Ob);

    gemm_proj<<<dim3(Lq / 128, Dm / 64), 256, 0, stream>>>(
        Ob, WprojT, bproj, out);
}